// Round 15
// baseline (144.435 us; speedup 1.0000x reference)
//
#include <hip/hip_runtime.h>
#include <hip/hip_bf16.h>
#include <stdint.h>

#define N_NODES 2048
#define WORDS   32
#define LABELS  16
#define FILTERS 16
#define FNODES  8
#define MAX_EGO 128
#define WL_LEVELS 4
#define IDCAP   256
#define TSLOTS  256

typedef unsigned long long u64;

__device__ __forceinline__ unsigned mixu(unsigned h) {
    h ^= h >> 16; h *= 0x7FEB352Du;
    h ^= h >> 15; h *= 0x846CA68Bu;
    h ^= h >> 16;
    return h;
}

// K1 (single prologue dispatch after a 512KB memset of Adense):
//  blocks [0, nbE):        edge-list atomics into Adense (1 edge / thread)
//  blocks [nbE, nbE+32):   hinit[v] = mixu(argmax16(x[v]) + 1) for 64 nodes each
//  block  nbE+32:          zero hash tables, filters + cross tables + self_f
__global__ void __launch_bounds__(64)
build_adj_kernel(const int* __restrict__ ei, int E2, u64* __restrict__ Adense,
                 const float* __restrict__ x, unsigned* __restrict__ hinit,
                 const float* __restrict__ Af, const float* __restrict__ Xf,
                 unsigned* __restrict__ tkeys, u64* __restrict__ tval0,
                 u64* __restrict__ tval1, float* __restrict__ selfg) {
    const int lane = threadIdx.x;
    const int nbE  = (E2 + 63) / 64;
    const int bid  = (int)blockIdx.x;

    if (bid < nbE) {
        int e = bid * 64 + lane;
        if (e < E2) {
            int s = ei[e], d = ei[E2 + e];
            atomicOr(&Adense[(size_t)s * WORDS + (d >> 6)], 1ull << (d & 63));
            atomicOr(&Adense[(size_t)d * WORDS + (s >> 6)], 1ull << (s & 63));
        }
        return;
    }
    if (bid < nbE + 32) {
        // initial-label precompute: node v = (bid-nbE)*64 + lane
        int v = (bid - nbE) * 64 + lane;
        const float4* xr = (const float4*)(x + (size_t)v * LABELS);
        float4 a0 = xr[0], a1 = xr[1], a2 = xr[2], a3 = xr[3];
        float vv[16] = {a0.x,a0.y,a0.z,a0.w,a1.x,a1.y,a1.z,a1.w,
                        a2.x,a2.y,a2.z,a2.w,a3.x,a3.y,a3.z,a3.w};
        float best = vv[0]; int bi = 0;
        #pragma unroll
        for (int c = 1; c < 16; ++c) { if (vv[c] > best) { best = vv[c]; bi = c; } }
        hinit[v] = mixu((unsigned)(bi + 1));
        return;
    }

    // ---- filters block: zero tables, then compute ----
    for (int t = lane; t < WL_LEVELS * TSLOTS; t += 64) {
        tkeys[t] = 0u; tval0[t] = 0ull; tval1[t] = 0ull;
    }
    __syncthreads();
    if (lane >= FILTERS) return;
    int f = lane;
    const float* Aff = Af + (size_t)f * FNODES * FNODES;
    unsigned row[FNODES];
    for (int m = 0; m < FNODES; ++m) {
        unsigned r = 0;
        for (int j = 0; j < FNODES; ++j)
            if (Aff[m * FNODES + j] > 0.f) r |= 1u << j;
        row[m] = r;
    }
    const float* Xff = Xf + (size_t)f * FNODES * LABELS;
    unsigned lab[FNODES];
    for (int m = 0; m < FNODES; ++m) {
        const float* xr = Xff + m * LABELS;
        float best = xr[0]; int bi = 0;
        for (int c = 1; c < LABELS; ++c) { float v = xr[c]; if (v > best) { best = v; bi = c; } }
        lab[m] = (unsigned)(bi + 1);
    }
    int lbl[FNODES];
    for (int m = 0; m < FNODES; ++m) lbl[m] = m;
    for (int it = 0; it < FNODES; ++it) {
        int nb2[FNODES];
        for (int m = 0; m < FNODES; ++m) {
            int mn = FNODES;
            for (int j = 0; j < FNODES; ++j)
                if ((row[m] >> j) & 1) mn = min(mn, lbl[j]);
            nb2[m] = mn;
        }
        for (int m = 0; m < FNODES; ++m) lbl[m] = min(lbl[m], nb2[m]);
    }
    int cnt[FNODES];
    for (int m = 0; m < FNODES; ++m) {
        int c = 0;
        for (int j = 0; j < FNODES; ++j) c += (lbl[j] == lbl[m]);
        cnt[m] = c;
    }
    int best = 0;
    for (int m = 1; m < FNODES; ++m) if (cnt[m] > cnt[best]) best = m;
    unsigned fm = 0;
    for (int m = 0; m < FNODES; ++m) if (lbl[m] == lbl[best]) fm |= 1u << m;
    unsigned brow[FNODES];
    for (int m = 0; m < FNODES; ++m) brow[m] = ((fm >> m) & 1) ? (row[m] & fm) : 0u;
    unsigned hh[FNODES];
    for (int m = 0; m < FNODES; ++m) hh[m] = mixu(lab[m]);
    float sf = 0.f;
    for (int t = 0; t < WL_LEVELS; ++t) {
        if (t > 0) {
            unsigned mx[FNODES], nh[FNODES];
            for (int m = 0; m < FNODES; ++m) mx[m] = mixu(hh[m]);
            for (int m = 0; m < FNODES; ++m) {
                unsigned msg = 0;
                for (int j = 0; j < FNODES; ++j)
                    if ((brow[m] >> j) & 1) msg += mx[j];
                nh[m] = mixu(hh[m] * 0x9E3779B1u + msg);
            }
            for (int m = 0; m < FNODES; ++m) hh[m] = nh[m];
        }
        for (int m = 0; m < FNODES; ++m) {
            if (!((fm >> m) & 1)) continue;
            unsigned key = hh[m];
            int p = (int)(key & (TSLOTS - 1));
            for (;;) {
                unsigned old = atomicCAS(&tkeys[t * TSLOTS + p], 0u, key);
                if (old == 0u || old == key) break;
                p = (p + 1) & (TSLOTS - 1);
            }
            if (f < 8) atomicAdd(&tval0[t * TSLOTS + p], 1ull << (8 * f));
            else       atomicAdd(&tval1[t * TSLOTS + p], 1ull << (8 * (f - 8)));
        }
        int c = 0;
        for (int m = 0; m < FNODES; ++m) if ((fm >> m) & 1)
            for (int j = 0; j < FNODES; ++j) if ((fm >> j) & 1) c += (hh[m] == hh[j]);
        sf += (float)c;
    }
    selfg[f] = sf;
}

// K2: one WAVE per seed (round-12 proven body; labels via hinit gather).
__global__ void __launch_bounds__(64)
ego_kernel(const unsigned* __restrict__ hinit,
           const u64* __restrict__ Adense,
           const unsigned* __restrict__ tkeys, const u64* __restrict__ tval0,
           const u64* __restrict__ tval1,
           const float* __restrict__ selfg, float* __restrict__ out) {
    const int i    = blockIdx.x;
    const int lane = threadIdx.x;
    const int w    = lane & 31;
    const int hwp  = lane >> 5;

    __shared__ u64 arow[WORDS];
    __shared__ u64 r2s[WORDS];
    __shared__ u64 mmask[WORDS];
    __shared__ unsigned pfx[WORDS];
    __shared__ unsigned idlist[IDCAP];
    __shared__ unsigned members[MAX_EGO];
    __shared__ __align__(16) unsigned h[MAX_EGO];
    __shared__ unsigned msgacc[MAX_EGO];
    __shared__ __align__(16) unsigned adjs[MAX_EGO][4];
    __shared__ float    selff_s[FILTERS];
    __shared__ unsigned cross_sh[FILTERS];
    __shared__ unsigned selfe_sh;

    if (lane < FILTERS) selff_s[lane] = selfg[lane];
    #pragma unroll
    for (int t = lane; t < MAX_EGO * 4; t += 64) ((unsigned*)adjs)[t] = 0;
    if (lane < WORDS) arow[lane] = Adense[(size_t)i * WORDS + lane];
    __syncthreads();

    // ---- extract N1 ids ----
    int n1;
    {
        u64 v = arow[w];
        int pc = __popcll(v);
        int incl = pc;
        for (int d = 1; d < 32; d <<= 1) {
            int t2 = __shfl_up(incl, d, 32);
            if (w >= d) incl += t2;
        }
        int ex = incl - pc;
        u64 vv = v; int r = 0;
        while (vv) {
            int b = __ffsll(vv) - 1; vv &= vv - 1;
            if (ex + r < IDCAP) idlist[ex + r] = (unsigned)((w << 6) + b);
            ++r;
        }
        n1 = min(__shfl(incl, 31, 32), IDCAP);
    }
    __syncthreads();

    // ---- r2 word: arow | I | OR of N1 rows (8-deep batched per half-wave) ----
    u64 racc = arow[w];
    if ((i >> 6) == w) racc |= 1ull << (i & 63);
    for (int t = hwp; t < n1; t += 16) {
        u64 vb[8];
        #pragma unroll
        for (int k = 0; k < 8; ++k) {
            int tk = t + 2 * k;
            vb[k] = (tk < n1) ? Adense[(size_t)idlist[tk] * WORDS + w] : 0ull;
        }
        racc |= vb[0] | vb[1] | vb[2] | vb[3] | vb[4] | vb[5] | vb[6] | vb[7];
    }
    racc |= __shfl_xor(racc, 32, 64);
    r2s[w] = racc;
    __syncthreads();

    // ---- extract N2 ids ----
    int n2;
    {
        u64 v = r2s[w];
        int pc = __popcll(v);
        int incl = pc;
        for (int d = 1; d < 32; d <<= 1) {
            int t2 = __shfl_up(incl, d, 32);
            if (w >= d) incl += t2;
        }
        int ex = incl - pc;
        u64 vv = v; int r = 0;
        while (vv) {
            int b = __ffsll(vv) - 1; vv &= vv - 1;
            if (ex + r < IDCAP) idlist[ex + r] = (unsigned)((w << 6) + b);
            ++r;
        }
        n2 = min(__shfl(incl, 31, 32), IDCAP);
    }
    __syncthreads();

    // ---- r3 word: r2 | OR of N2 rows (8-deep batched) ----
    u64 acc3 = racc;
    for (int t = hwp; t < n2; t += 16) {
        u64 vb[8];
        #pragma unroll
        for (int k = 0; k < 8; ++k) {
            int tk = t + 2 * k;
            vb[k] = (tk < n2) ? Adense[(size_t)idlist[tk] * WORDS + w] : 0ull;
        }
        acc3 |= vb[0] | vb[1] | vb[2] | vb[3] | vb[4] | vb[5] | vb[6] | vb[7];
    }
    acc3 |= __shfl_xor(acc3, 32, 64);

    // ---- member mask trim (seed + 127 smallest-index members) ----
    int S;
    {
        u64 v = acc3;
        int seedw = i >> 6;
        u64 seedbit = 1ull << (i & 63);
        if (w == seedw) v &= ~seedbit;
        int pc = __popcll(v);
        int incl = pc;
        for (int d = 1; d < 32; d <<= 1) {
            int t2 = __shfl_up(incl, d, 32);
            if (w >= d) incl += t2;
        }
        int excl = incl - pc;
        const int keep = MAX_EGO - 1;
        if (excl >= keep) {
            v = 0;
        } else {
            int allow = keep - excl;
            while (pc > allow) {
                v &= ~(1ull << (63 - __clzll(v)));
                --pc;
            }
        }
        if (w == seedw) v |= seedbit;
        mmask[w] = v;
        int pc2 = __popcll(v);
        int incl2 = pc2;
        for (int d = 1; d < 32; d <<= 1) {
            int t2 = __shfl_up(incl2, d, 32);
            if (w >= d) incl2 += t2;
        }
        int ex2 = incl2 - pc2;
        pfx[w] = (unsigned)ex2;
        u64 vv = v;
        int r = 0;
        while (vv) {
            int b = __ffsll(vv) - 1;
            vv &= vv - 1;
            members[ex2 + r] = (unsigned)((w << 6) + b);
            ++r;
        }
        S = __shfl(incl2, 31, 32);
    }
    __syncthreads();
    const int s0 = lane, s1 = lane + 64;
    const bool p0 = (s0 < S), p1 = (s1 < S);

    // ---- initial WL labels: one gather from precomputed hinit ----
    unsigned hv0 = 0, hv1 = 0;
    if (p0) { hv0 = hinit[members[s0]]; h[s0] = hv0; }
    if (p1) { hv1 = hinit[members[s1]]; h[s1] = hv1; }

    // ---- compact ego adjacency (half-wave per slot, 8-deep load batch) ----
    {
        const u64 mw = mmask[w];
        const unsigned base = pfx[w];
        for (int t = hwp; t < S; t += 16) {
            u64 vb[8];
            int ti[8];
            #pragma unroll
            for (int k = 0; k < 8; ++k) {
                ti[k] = t + 2 * k;
                vb[k] = (ti[k] < S) ? (Adense[(size_t)members[ti[k]] * WORDS + w] & mw) : 0ull;
            }
            #pragma unroll
            for (int k = 0; k < 8; ++k) {
                u64 v = vb[k];
                while (v) {
                    int b = __ffsll(v) - 1; v &= v - 1;
                    int slot = (int)base + __popcll(mw & ((1ull << b) - 1));
                    atomicOr(&adjs[ti[k]][slot >> 5], 1u << (slot & 31));
                }
            }
        }
    }
    __syncthreads();

    uint4 aw0 = *(const uint4*)adjs[s0];
    uint4 aw1 = *(const uint4*)adjs[s1];

    // ---- 4 WL levels: scatter-msg refine + probe-based cross + self scan ----
    u64 accA = 0, accB = 0;
    unsigned selfeReg = 0;

    for (int t = 0; t < WL_LEVELS; ++t) {
        if (t > 0) {
            msgacc[lane] = 0u; msgacc[lane + 64] = 0u;
            __syncthreads();
            if (p0) {
                unsigned mixv = mixu(hv0);
                unsigned bw[4] = {aw0.x, aw0.y, aw0.z, aw0.w};
                #pragma unroll
                for (int ww = 0; ww < 4; ++ww) {
                    unsigned bits = bw[ww];
                    while (bits) { int l = __ffs(bits) - 1; bits &= bits - 1;
                                   atomicAdd(&msgacc[(ww << 5) + l], mixv); }
                }
            }
            if (p1) {
                unsigned mixv = mixu(hv1);
                unsigned bw[4] = {aw1.x, aw1.y, aw1.z, aw1.w};
                #pragma unroll
                for (int ww = 0; ww < 4; ++ww) {
                    unsigned bits = bw[ww];
                    while (bits) { int l = __ffs(bits) - 1; bits &= bits - 1;
                                   atomicAdd(&msgacc[(ww << 5) + l], mixv); }
                }
            }
            __syncthreads();
            if (p0) { hv0 = mixu(hv0 * 0x9E3779B1u + msgacc[s0]); h[s0] = hv0; }
            if (p1) { hv1 = mixu(hv1 * 0x9E3779B1u + msgacc[s1]); h[s1] = hv1; }
            __syncthreads();
        }

        const unsigned* tk = tkeys + t * TSLOTS;
        if (p0) {
            int p = (int)(hv0 & (TSLOTS - 1));
            unsigned k;
            while ((k = tk[p]) != 0u && k != hv0) p = (p + 1) & (TSLOTS - 1);
            if (k == hv0) { accA += tval0[t * TSLOTS + p]; accB += tval1[t * TSLOTS + p]; }
        }
        if (p1) {
            int p = (int)(hv1 & (TSLOTS - 1));
            unsigned k;
            while ((k = tk[p]) != 0u && k != hv1) p = (p + 1) & (TSLOTS - 1);
            if (k == hv1) { accA += tval0[t * TSLOTS + p]; accB += tval1[t * TSLOTS + p]; }
        }

        {   // self_e: scan h[0..S) via uint4 reads + scalar tail
            unsigned ce = 0;
            const int quads = S >> 2;
            const uint4* h4 = (const uint4*)h;
            for (int qq = 0; qq < quads; ++qq) {
                uint4 hh = h4[qq];
                if (p0) ce += (unsigned)(hh.x == hv0) + (unsigned)(hh.y == hv0)
                            + (unsigned)(hh.z == hv0) + (unsigned)(hh.w == hv0);
                if (p1) ce += (unsigned)(hh.x == hv1) + (unsigned)(hh.y == hv1)
                            + (unsigned)(hh.z == hv1) + (unsigned)(hh.w == hv1);
            }
            for (int l = quads << 2; l < S; ++l) {
                unsigned hl = h[l];
                if (p0) ce += (unsigned)(hl == hv0);
                if (p1) ce += (unsigned)(hl == hv1);
            }
            selfeReg += ce;
        }
        __syncthreads();
    }

    // ---- unpack packed cross counts, wave reduction, output ----
    unsigned crossReg[FILTERS];
    #pragma unroll
    for (int k = 0; k < 8; ++k) {
        crossReg[k]     = (unsigned)((accA >> (8 * k)) & 0xFFull);
        crossReg[k + 8] = (unsigned)((accB >> (8 * k)) & 0xFFull);
    }
    #pragma unroll
    for (int f = 0; f < FILTERS; ++f) {
        unsigned v = crossReg[f];
        for (int o = 32; o > 0; o >>= 1) v += __shfl_down(v, o, 64);
        crossReg[f] = v;
    }
    {
        unsigned v = selfeReg;
        for (int o = 32; o > 0; o >>= 1) v += __shfl_down(v, o, 64);
        selfeReg = v;
    }
    if (lane == 0) {
        #pragma unroll
        for (int f = 0; f < FILTERS; ++f) cross_sh[f] = crossReg[f];
        selfe_sh = selfeReg;
    }
    __syncthreads();
    if (lane < FILTERS) {
        float se = (float)selfe_sh;
        float sf = selff_s[lane];
        float denom = sqrtf(se * sf);
        float v = (denom > 0.f) ? ((float)cross_sh[lane] / denom) : 0.f;
        out[(size_t)i * FILTERS + lane] = v;
    }
}

extern "C" void kernel_launch(void* const* d_in, const int* in_sizes, int n_in,
                              void* d_out, int out_size, void* d_ws, size_t ws_size,
                              hipStream_t stream) {
    const float* x  = (const float*)d_in[0];
    const int*   ei = (const int*)d_in[1];
    // d_in[2] = batch (unused: single graph)
    const float* A  = (const float*)d_in[3];
    const float* X  = (const float*)d_in[4];
    float* out = (float*)d_out;
    int E2 = in_sizes[1] / 2;   // directed edge count (both directions present)

    char* ws = (char*)d_ws;
    const size_t ADJ_BYTES = (size_t)N_NODES * WORDS * sizeof(u64); // 512 KB
    u64* Adense = (u64*)(ws);
    unsigned* tkeys = (unsigned*)(ws + ADJ_BYTES);                   // 4 KB
    u64*      tval0 = (u64*)     (ws + ADJ_BYTES + 4096);            // 8 KB
    u64*      tval1 = (u64*)     (ws + ADJ_BYTES + 4096 + 8192);     // 8 KB
    float*    selfg = (float*)   (ws + ADJ_BYTES + 4096 + 16384);    // 256 B
    unsigned* hinit = (unsigned*)(ws + ADJ_BYTES + 4096 + 16384 + 256); // 8 KB

    hipMemsetAsync(Adense, 0, ADJ_BYTES, stream);   // adjacency only
    int nbE = (E2 + 63) / 64;
    build_adj_kernel<<<nbE + 32 + 1, 64, 0, stream>>>(ei, E2, Adense, x, hinit,
                                                      A, X, tkeys, tval0, tval1, selfg);
    ego_kernel<<<N_NODES, 64, 0, stream>>>(hinit, Adense, tkeys, tval0, tval1, selfg, out);
}

// Round 16
// 124.360 us; speedup vs baseline: 1.1614x; 1.1614x over previous
//
#include <hip/hip_runtime.h>
#include <hip/hip_bf16.h>
#include <stdint.h>

#define N_NODES 2048
#define WORDS   32
#define LABELS  16
#define FILTERS 16
#define FNODES  8
#define MAX_EGO 128
#define WL_LEVELS 4
#define IDCAP   256
#define TSLOTS  256

typedef unsigned long long u64;

__device__ __forceinline__ unsigned mixu(unsigned h) {
    h ^= h >> 16; h *= 0x7FEB352Du;
    h ^= h >> 15; h *= 0x846CA68Bu;
    h ^= h >> 16;
    return h;
}

// K1 (single prologue dispatch after a 512KB memset of Adense):
//  blocks [0, nbE):        edge-list atomics into Adense (1 edge / thread)
//  blocks [nbE, nbE+32):   hinit[v] = mixu(argmax16(x[v]) + 1)
//  block  nbE+32:          filters + cross tables built in LDS, dumped to global
__global__ void __launch_bounds__(64)
build_adj_kernel(const int* __restrict__ ei, int E2, u64* __restrict__ Adense,
                 const float* __restrict__ x, unsigned* __restrict__ hinit,
                 const float* __restrict__ Af, const float* __restrict__ Xf,
                 unsigned* __restrict__ tkeys, u64* __restrict__ tval0,
                 u64* __restrict__ tval1, float* __restrict__ selfg) {
    const int lane = threadIdx.x;
    const int nbE  = (E2 + 63) / 64;
    const int bid  = (int)blockIdx.x;

    if (bid < nbE) {
        int e = bid * 64 + lane;
        if (e < E2) {
            int s = ei[e], d = ei[E2 + e];
            atomicOr(&Adense[(size_t)s * WORDS + (d >> 6)], 1ull << (d & 63));
            atomicOr(&Adense[(size_t)d * WORDS + (s >> 6)], 1ull << (s & 63));
        }
        return;
    }
    if (bid < nbE + 32) {
        int v = (bid - nbE) * 64 + lane;
        const float4* xr = (const float4*)(x + (size_t)v * LABELS);
        float4 a0 = xr[0], a1 = xr[1], a2 = xr[2], a3 = xr[3];
        float vv[16] = {a0.x,a0.y,a0.z,a0.w,a1.x,a1.y,a1.z,a1.w,
                        a2.x,a2.y,a2.z,a2.w,a3.x,a3.y,a3.z,a3.w};
        float best = vv[0]; int bi = 0;
        #pragma unroll
        for (int c = 1; c < 16; ++c) { if (vv[c] > best) { best = vv[c]; bi = c; } }
        hinit[v] = mixu((unsigned)(bi + 1));
        return;
    }

    // ---- filters block: tables in LDS (fast atomics), then coalesced dump ----
    __shared__ unsigned ltk[WL_LEVELS * TSLOTS];   // 4 KB
    __shared__ u64 ltv0[WL_LEVELS * TSLOTS];       // 8 KB
    __shared__ u64 ltv1[WL_LEVELS * TSLOTS];       // 8 KB
    for (int t = lane; t < WL_LEVELS * TSLOTS; t += 64) {
        ltk[t] = 0u; ltv0[t] = 0ull; ltv1[t] = 0ull;
    }
    __syncthreads();

    if (lane < FILTERS) {
        int f = lane;
        const float* Aff = Af + (size_t)f * FNODES * FNODES;
        unsigned row[FNODES];
        for (int m = 0; m < FNODES; ++m) {
            unsigned r = 0;
            for (int j = 0; j < FNODES; ++j)
                if (Aff[m * FNODES + j] > 0.f) r |= 1u << j;
            row[m] = r;
        }
        const float* Xff = Xf + (size_t)f * FNODES * LABELS;
        unsigned lab[FNODES];
        for (int m = 0; m < FNODES; ++m) {
            const float* xr = Xff + m * LABELS;
            float best = xr[0]; int bi = 0;
            for (int c = 1; c < LABELS; ++c) { float v = xr[c]; if (v > best) { best = v; bi = c; } }
            lab[m] = (unsigned)(bi + 1);
        }
        int lbl[FNODES];
        for (int m = 0; m < FNODES; ++m) lbl[m] = m;
        for (int it = 0; it < FNODES; ++it) {
            int nb2[FNODES];
            for (int m = 0; m < FNODES; ++m) {
                int mn = FNODES;
                for (int j = 0; j < FNODES; ++j)
                    if ((row[m] >> j) & 1) mn = min(mn, lbl[j]);
                nb2[m] = mn;
            }
            for (int m = 0; m < FNODES; ++m) lbl[m] = min(lbl[m], nb2[m]);
        }
        int cnt[FNODES];
        for (int m = 0; m < FNODES; ++m) {
            int c = 0;
            for (int j = 0; j < FNODES; ++j) c += (lbl[j] == lbl[m]);
            cnt[m] = c;
        }
        int best = 0;
        for (int m = 1; m < FNODES; ++m) if (cnt[m] > cnt[best]) best = m;
        unsigned fm = 0;
        for (int m = 0; m < FNODES; ++m) if (lbl[m] == lbl[best]) fm |= 1u << m;
        unsigned brow[FNODES];
        for (int m = 0; m < FNODES; ++m) brow[m] = ((fm >> m) & 1) ? (row[m] & fm) : 0u;
        unsigned hh[FNODES];
        for (int m = 0; m < FNODES; ++m) hh[m] = mixu(lab[m]);
        float sf = 0.f;
        for (int t = 0; t < WL_LEVELS; ++t) {
            if (t > 0) {
                unsigned mx[FNODES], nh[FNODES];
                for (int m = 0; m < FNODES; ++m) mx[m] = mixu(hh[m]);
                for (int m = 0; m < FNODES; ++m) {
                    unsigned msg = 0;
                    for (int j = 0; j < FNODES; ++j)
                        if ((brow[m] >> j) & 1) msg += mx[j];
                    nh[m] = mixu(hh[m] * 0x9E3779B1u + msg);
                }
                for (int m = 0; m < FNODES; ++m) hh[m] = nh[m];
            }
            for (int m = 0; m < FNODES; ++m) {
                if (!((fm >> m) & 1)) continue;
                unsigned key = hh[m];
                int p = (int)(key & (TSLOTS - 1));
                for (;;) {
                    unsigned old = atomicCAS(&ltk[t * TSLOTS + p], 0u, key);
                    if (old == 0u || old == key) break;
                    p = (p + 1) & (TSLOTS - 1);
                }
                if (f < 8) atomicAdd(&ltv0[t * TSLOTS + p], 1ull << (8 * f));
                else       atomicAdd(&ltv1[t * TSLOTS + p], 1ull << (8 * (f - 8)));
            }
            int c = 0;
            for (int m = 0; m < FNODES; ++m) if ((fm >> m) & 1)
                for (int j = 0; j < FNODES; ++j) if ((fm >> j) & 1) c += (hh[m] == hh[j]);
            sf += (float)c;
        }
        selfg[f] = sf;
    }
    __syncthreads();
    // coalesced dump of the 20 KB of tables
    for (int t = lane; t < WL_LEVELS * TSLOTS; t += 64) {
        tkeys[t] = ltk[t]; tval0[t] = ltv0[t]; tval1[t] = ltv1[t];
    }
}

// K2: one WAVE per seed (round-12 proven body; labels via hinit gather).
__global__ void __launch_bounds__(64)
ego_kernel(const unsigned* __restrict__ hinit,
           const u64* __restrict__ Adense,
           const unsigned* __restrict__ tkeys, const u64* __restrict__ tval0,
           const u64* __restrict__ tval1,
           const float* __restrict__ selfg, float* __restrict__ out) {
    const int i    = blockIdx.x;
    const int lane = threadIdx.x;
    const int w    = lane & 31;
    const int hwp  = lane >> 5;

    __shared__ u64 arow[WORDS];
    __shared__ u64 r2s[WORDS];
    __shared__ u64 mmask[WORDS];
    __shared__ unsigned pfx[WORDS];
    __shared__ unsigned idlist[IDCAP];
    __shared__ unsigned members[MAX_EGO];
    __shared__ __align__(16) unsigned h[MAX_EGO];
    __shared__ unsigned msgacc[MAX_EGO];
    __shared__ __align__(16) unsigned adjs[MAX_EGO][4];
    __shared__ float    selff_s[FILTERS];
    __shared__ unsigned cross_sh[FILTERS];
    __shared__ unsigned selfe_sh;

    if (lane < FILTERS) selff_s[lane] = selfg[lane];
    #pragma unroll
    for (int t = lane; t < MAX_EGO * 4; t += 64) ((unsigned*)adjs)[t] = 0;
    if (lane < WORDS) arow[lane] = Adense[(size_t)i * WORDS + lane];
    __syncthreads();

    // ---- extract N1 ids ----
    int n1;
    {
        u64 v = arow[w];
        int pc = __popcll(v);
        int incl = pc;
        for (int d = 1; d < 32; d <<= 1) {
            int t2 = __shfl_up(incl, d, 32);
            if (w >= d) incl += t2;
        }
        int ex = incl - pc;
        u64 vv = v; int r = 0;
        while (vv) {
            int b = __ffsll(vv) - 1; vv &= vv - 1;
            if (ex + r < IDCAP) idlist[ex + r] = (unsigned)((w << 6) + b);
            ++r;
        }
        n1 = min(__shfl(incl, 31, 32), IDCAP);
    }
    __syncthreads();

    // ---- r2 word: arow | I | OR of N1 rows (8-deep batched per half-wave) ----
    u64 racc = arow[w];
    if ((i >> 6) == w) racc |= 1ull << (i & 63);
    for (int t = hwp; t < n1; t += 16) {
        u64 vb[8];
        #pragma unroll
        for (int k = 0; k < 8; ++k) {
            int tk = t + 2 * k;
            vb[k] = (tk < n1) ? Adense[(size_t)idlist[tk] * WORDS + w] : 0ull;
        }
        racc |= vb[0] | vb[1] | vb[2] | vb[3] | vb[4] | vb[5] | vb[6] | vb[7];
    }
    racc |= __shfl_xor(racc, 32, 64);
    r2s[w] = racc;
    __syncthreads();

    // ---- extract N2 ids ----
    int n2;
    {
        u64 v = r2s[w];
        int pc = __popcll(v);
        int incl = pc;
        for (int d = 1; d < 32; d <<= 1) {
            int t2 = __shfl_up(incl, d, 32);
            if (w >= d) incl += t2;
        }
        int ex = incl - pc;
        u64 vv = v; int r = 0;
        while (vv) {
            int b = __ffsll(vv) - 1; vv &= vv - 1;
            if (ex + r < IDCAP) idlist[ex + r] = (unsigned)((w << 6) + b);
            ++r;
        }
        n2 = min(__shfl(incl, 31, 32), IDCAP);
    }
    __syncthreads();

    // ---- r3 word: r2 | OR of N2 rows (8-deep batched) ----
    u64 acc3 = racc;
    for (int t = hwp; t < n2; t += 16) {
        u64 vb[8];
        #pragma unroll
        for (int k = 0; k < 8; ++k) {
            int tk = t + 2 * k;
            vb[k] = (tk < n2) ? Adense[(size_t)idlist[tk] * WORDS + w] : 0ull;
        }
        acc3 |= vb[0] | vb[1] | vb[2] | vb[3] | vb[4] | vb[5] | vb[6] | vb[7];
    }
    acc3 |= __shfl_xor(acc3, 32, 64);

    // ---- member mask trim (seed + 127 smallest-index members) ----
    int S;
    {
        u64 v = acc3;
        int seedw = i >> 6;
        u64 seedbit = 1ull << (i & 63);
        if (w == seedw) v &= ~seedbit;
        int pc = __popcll(v);
        int incl = pc;
        for (int d = 1; d < 32; d <<= 1) {
            int t2 = __shfl_up(incl, d, 32);
            if (w >= d) incl += t2;
        }
        int excl = incl - pc;
        const int keep = MAX_EGO - 1;
        if (excl >= keep) {
            v = 0;
        } else {
            int allow = keep - excl;
            while (pc > allow) {
                v &= ~(1ull << (63 - __clzll(v)));
                --pc;
            }
        }
        if (w == seedw) v |= seedbit;
        mmask[w] = v;
        int pc2 = __popcll(v);
        int incl2 = pc2;
        for (int d = 1; d < 32; d <<= 1) {
            int t2 = __shfl_up(incl2, d, 32);
            if (w >= d) incl2 += t2;
        }
        int ex2 = incl2 - pc2;
        pfx[w] = (unsigned)ex2;
        u64 vv = v;
        int r = 0;
        while (vv) {
            int b = __ffsll(vv) - 1;
            vv &= vv - 1;
            members[ex2 + r] = (unsigned)((w << 6) + b);
            ++r;
        }
        S = __shfl(incl2, 31, 32);
    }
    __syncthreads();
    const int s0 = lane, s1 = lane + 64;
    const bool p0 = (s0 < S), p1 = (s1 < S);

    // ---- initial WL labels: one gather from precomputed hinit ----
    unsigned hv0 = 0, hv1 = 0;
    if (p0) { hv0 = hinit[members[s0]]; h[s0] = hv0; }
    if (p1) { hv1 = hinit[members[s1]]; h[s1] = hv1; }

    // ---- compact ego adjacency (half-wave per slot, 8-deep load batch) ----
    {
        const u64 mw = mmask[w];
        const unsigned base = pfx[w];
        for (int t = hwp; t < S; t += 16) {
            u64 vb[8];
            int ti[8];
            #pragma unroll
            for (int k = 0; k < 8; ++k) {
                ti[k] = t + 2 * k;
                vb[k] = (ti[k] < S) ? (Adense[(size_t)members[ti[k]] * WORDS + w] & mw) : 0ull;
            }
            #pragma unroll
            for (int k = 0; k < 8; ++k) {
                u64 v = vb[k];
                while (v) {
                    int b = __ffsll(v) - 1; v &= v - 1;
                    int slot = (int)base + __popcll(mw & ((1ull << b) - 1));
                    atomicOr(&adjs[ti[k]][slot >> 5], 1u << (slot & 31));
                }
            }
        }
    }
    __syncthreads();

    uint4 aw0 = *(const uint4*)adjs[s0];
    uint4 aw1 = *(const uint4*)adjs[s1];

    // ---- 4 WL levels: scatter-msg refine + probe-based cross + self scan ----
    u64 accA = 0, accB = 0;
    unsigned selfeReg = 0;

    for (int t = 0; t < WL_LEVELS; ++t) {
        if (t > 0) {
            msgacc[lane] = 0u; msgacc[lane + 64] = 0u;
            __syncthreads();
            if (p0) {
                unsigned mixv = mixu(hv0);
                unsigned bw[4] = {aw0.x, aw0.y, aw0.z, aw0.w};
                #pragma unroll
                for (int ww = 0; ww < 4; ++ww) {
                    unsigned bits = bw[ww];
                    while (bits) { int l = __ffs(bits) - 1; bits &= bits - 1;
                                   atomicAdd(&msgacc[(ww << 5) + l], mixv); }
                }
            }
            if (p1) {
                unsigned mixv = mixu(hv1);
                unsigned bw[4] = {aw1.x, aw1.y, aw1.z, aw1.w};
                #pragma unroll
                for (int ww = 0; ww < 4; ++ww) {
                    unsigned bits = bw[ww];
                    while (bits) { int l = __ffs(bits) - 1; bits &= bits - 1;
                                   atomicAdd(&msgacc[(ww << 5) + l], mixv); }
                }
            }
            __syncthreads();
            if (p0) { hv0 = mixu(hv0 * 0x9E3779B1u + msgacc[s0]); h[s0] = hv0; }
            if (p1) { hv1 = mixu(hv1 * 0x9E3779B1u + msgacc[s1]); h[s1] = hv1; }
            __syncthreads();
        }

        const unsigned* tk = tkeys + t * TSLOTS;
        if (p0) {
            int p = (int)(hv0 & (TSLOTS - 1));
            unsigned k;
            while ((k = tk[p]) != 0u && k != hv0) p = (p + 1) & (TSLOTS - 1);
            if (k == hv0) { accA += tval0[t * TSLOTS + p]; accB += tval1[t * TSLOTS + p]; }
        }
        if (p1) {
            int p = (int)(hv1 & (TSLOTS - 1));
            unsigned k;
            while ((k = tk[p]) != 0u && k != hv1) p = (p + 1) & (TSLOTS - 1);
            if (k == hv1) { accA += tval0[t * TSLOTS + p]; accB += tval1[t * TSLOTS + p]; }
        }

        {   // self_e: scan h[0..S) via uint4 reads + scalar tail
            unsigned ce = 0;
            const int quads = S >> 2;
            const uint4* h4 = (const uint4*)h;
            for (int qq = 0; qq < quads; ++qq) {
                uint4 hh = h4[qq];
                if (p0) ce += (unsigned)(hh.x == hv0) + (unsigned)(hh.y == hv0)
                            + (unsigned)(hh.z == hv0) + (unsigned)(hh.w == hv0);
                if (p1) ce += (unsigned)(hh.x == hv1) + (unsigned)(hh.y == hv1)
                            + (unsigned)(hh.z == hv1) + (unsigned)(hh.w == hv1);
            }
            for (int l = quads << 2; l < S; ++l) {
                unsigned hl = h[l];
                if (p0) ce += (unsigned)(hl == hv0);
                if (p1) ce += (unsigned)(hl == hv1);
            }
            selfeReg += ce;
        }
        __syncthreads();
    }

    // ---- unpack packed cross counts, wave reduction, output ----
    unsigned crossReg[FILTERS];
    #pragma unroll
    for (int k = 0; k < 8; ++k) {
        crossReg[k]     = (unsigned)((accA >> (8 * k)) & 0xFFull);
        crossReg[k + 8] = (unsigned)((accB >> (8 * k)) & 0xFFull);
    }
    #pragma unroll
    for (int f = 0; f < FILTERS; ++f) {
        unsigned v = crossReg[f];
        for (int o = 32; o > 0; o >>= 1) v += __shfl_down(v, o, 64);
        crossReg[f] = v;
    }
    {
        unsigned v = selfeReg;
        for (int o = 32; o > 0; o >>= 1) v += __shfl_down(v, o, 64);
        selfeReg = v;
    }
    if (lane == 0) {
        #pragma unroll
        for (int f = 0; f < FILTERS; ++f) cross_sh[f] = crossReg[f];
        selfe_sh = selfeReg;
    }
    __syncthreads();
    if (lane < FILTERS) {
        float se = (float)selfe_sh;
        float sf = selff_s[lane];
        float denom = sqrtf(se * sf);
        float v = (denom > 0.f) ? ((float)cross_sh[lane] / denom) : 0.f;
        out[(size_t)i * FILTERS + lane] = v;
    }
}

extern "C" void kernel_launch(void* const* d_in, const int* in_sizes, int n_in,
                              void* d_out, int out_size, void* d_ws, size_t ws_size,
                              hipStream_t stream) {
    const float* x  = (const float*)d_in[0];
    const int*   ei = (const int*)d_in[1];
    // d_in[2] = batch (unused: single graph)
    const float* A  = (const float*)d_in[3];
    const float* X  = (const float*)d_in[4];
    float* out = (float*)d_out;
    int E2 = in_sizes[1] / 2;   // directed edge count (both directions present)

    char* ws = (char*)d_ws;
    const size_t ADJ_BYTES = (size_t)N_NODES * WORDS * sizeof(u64); // 512 KB
    u64* Adense = (u64*)(ws);
    unsigned* tkeys = (unsigned*)(ws + ADJ_BYTES);                   // 4 KB
    u64*      tval0 = (u64*)     (ws + ADJ_BYTES + 4096);            // 8 KB
    u64*      tval1 = (u64*)     (ws + ADJ_BYTES + 4096 + 8192);     // 8 KB
    float*    selfg = (float*)   (ws + ADJ_BYTES + 4096 + 16384);    // 256 B
    unsigned* hinit = (unsigned*)(ws + ADJ_BYTES + 4096 + 16384 + 256); // 8 KB

    hipMemsetAsync(Adense, 0, ADJ_BYTES, stream);   // adjacency only
    int nbE = (E2 + 63) / 64;
    build_adj_kernel<<<nbE + 32 + 1, 64, 0, stream>>>(ei, E2, Adense, x, hinit,
                                                      A, X, tkeys, tval0, tval1, selfg);
    ego_kernel<<<N_NODES, 64, 0, stream>>>(hinit, Adense, tkeys, tval0, tval1, selfg, out);
}

// Round 18
// 117.258 us; speedup vs baseline: 1.2318x; 1.0606x over previous
//
#include <hip/hip_runtime.h>
#include <hip/hip_bf16.h>
#include <stdint.h>

#define N_NODES 2048
#define WORDS   32
#define LABELS  16
#define FILTERS 16
#define FNODES  8
#define MAX_EGO 128
#define WL_LEVELS 4
#define IDCAP   256
#define TSLOTS  256

typedef unsigned long long u64;

__device__ __forceinline__ unsigned mixu(unsigned h) {
    h ^= h >> 16; h *= 0x7FEB352Du;
    h ^= h >> 15; h *= 0x846CA68Bu;
    h ^= h >> 16;
    return h;
}

// K1 (single prologue dispatch after a 512KB memset of Adense):
//  blocks [0, nbE):        edge-list atomics into Adense (1 edge / thread)
//  blocks [nbE, nbE+32):   hinit[v] = mixu(argmax16(x[v]) + 1)
//  block  nbE+32:          filters + cross tables built in LDS, dumped to global
__global__ void __launch_bounds__(64)
build_adj_kernel(const int* __restrict__ ei, int E2, u64* __restrict__ Adense,
                 const float* __restrict__ x, unsigned* __restrict__ hinit,
                 const float* __restrict__ Af, const float* __restrict__ Xf,
                 unsigned* __restrict__ tkeys, u64* __restrict__ tval0,
                 u64* __restrict__ tval1, float* __restrict__ selfg) {
    const int lane = threadIdx.x;
    const int nbE  = (E2 + 63) / 64;
    const int bid  = (int)blockIdx.x;

    if (bid < nbE) {
        int e = bid * 64 + lane;
        if (e < E2) {
            int s = ei[e], d = ei[E2 + e];
            atomicOr(&Adense[(size_t)s * WORDS + (d >> 6)], 1ull << (d & 63));
            atomicOr(&Adense[(size_t)d * WORDS + (s >> 6)], 1ull << (s & 63));
        }
        return;
    }
    if (bid < nbE + 32) {
        int v = (bid - nbE) * 64 + lane;
        const float4* xr = (const float4*)(x + (size_t)v * LABELS);
        float4 a0 = xr[0], a1 = xr[1], a2 = xr[2], a3 = xr[3];
        float vv[16] = {a0.x,a0.y,a0.z,a0.w,a1.x,a1.y,a1.z,a1.w,
                        a2.x,a2.y,a2.z,a2.w,a3.x,a3.y,a3.z,a3.w};
        float best = vv[0]; int bi = 0;
        #pragma unroll
        for (int c = 1; c < 16; ++c) { if (vv[c] > best) { best = vv[c]; bi = c; } }
        hinit[v] = mixu((unsigned)(bi + 1));
        return;
    }

    // ---- filters block: tables in LDS (fast atomics), then coalesced dump ----
    __shared__ unsigned ltk[WL_LEVELS * TSLOTS];   // 4 KB
    __shared__ u64 ltv0[WL_LEVELS * TSLOTS];       // 8 KB
    __shared__ u64 ltv1[WL_LEVELS * TSLOTS];       // 8 KB
    for (int t = lane; t < WL_LEVELS * TSLOTS; t += 64) {
        ltk[t] = 0u; ltv0[t] = 0ull; ltv1[t] = 0ull;
    }
    __syncthreads();

    if (lane < FILTERS) {
        int f = lane;
        const float* Aff = Af + (size_t)f * FNODES * FNODES;
        unsigned row[FNODES];
        for (int m = 0; m < FNODES; ++m) {
            unsigned r = 0;
            for (int j = 0; j < FNODES; ++j)
                if (Aff[m * FNODES + j] > 0.f) r |= 1u << j;
            row[m] = r;
        }
        const float* Xff = Xf + (size_t)f * FNODES * LABELS;
        unsigned lab[FNODES];
        for (int m = 0; m < FNODES; ++m) {
            const float* xr = Xff + m * LABELS;
            float best = xr[0]; int bi = 0;
            for (int c = 1; c < LABELS; ++c) { float v = xr[c]; if (v > best) { best = v; bi = c; } }
            lab[m] = (unsigned)(bi + 1);
        }
        int lbl[FNODES];
        for (int m = 0; m < FNODES; ++m) lbl[m] = m;
        for (int it = 0; it < FNODES; ++it) {
            int nb2[FNODES];
            for (int m = 0; m < FNODES; ++m) {
                int mn = FNODES;
                for (int j = 0; j < FNODES; ++j)
                    if ((row[m] >> j) & 1) mn = min(mn, lbl[j]);
                nb2[m] = mn;
            }
            for (int m = 0; m < FNODES; ++m) lbl[m] = min(lbl[m], nb2[m]);
        }
        int cnt[FNODES];
        for (int m = 0; m < FNODES; ++m) {
            int c = 0;
            for (int j = 0; j < FNODES; ++j) c += (lbl[j] == lbl[m]);
            cnt[m] = c;
        }
        int best = 0;
        for (int m = 1; m < FNODES; ++m) if (cnt[m] > cnt[best]) best = m;
        unsigned fm = 0;
        for (int m = 0; m < FNODES; ++m) if (lbl[m] == lbl[best]) fm |= 1u << m;
        unsigned brow[FNODES];
        for (int m = 0; m < FNODES; ++m) brow[m] = ((fm >> m) & 1) ? (row[m] & fm) : 0u;
        unsigned hh[FNODES];
        for (int m = 0; m < FNODES; ++m) hh[m] = mixu(lab[m]);
        float sf = 0.f;
        for (int t = 0; t < WL_LEVELS; ++t) {
            if (t > 0) {
                unsigned mx[FNODES], nh[FNODES];
                for (int m = 0; m < FNODES; ++m) mx[m] = mixu(hh[m]);
                for (int m = 0; m < FNODES; ++m) {
                    unsigned msg = 0;
                    for (int j = 0; j < FNODES; ++j)
                        if ((brow[m] >> j) & 1) msg += mx[j];
                    nh[m] = mixu(hh[m] * 0x9E3779B1u + msg);
                }
                for (int m = 0; m < FNODES; ++m) hh[m] = nh[m];
            }
            for (int m = 0; m < FNODES; ++m) {
                if (!((fm >> m) & 1)) continue;
                unsigned key = hh[m];
                int p = (int)(key & (TSLOTS - 1));
                for (;;) {
                    unsigned old = atomicCAS(&ltk[t * TSLOTS + p], 0u, key);
                    if (old == 0u || old == key) break;
                    p = (p + 1) & (TSLOTS - 1);
                }
                if (f < 8) atomicAdd(&ltv0[t * TSLOTS + p], 1ull << (8 * f));
                else       atomicAdd(&ltv1[t * TSLOTS + p], 1ull << (8 * (f - 8)));
            }
            int c = 0;
            for (int m = 0; m < FNODES; ++m) if ((fm >> m) & 1)
                for (int j = 0; j < FNODES; ++j) if ((fm >> j) & 1) c += (hh[m] == hh[j]);
            sf += (float)c;
        }
        selfg[f] = sf;
    }
    __syncthreads();
    // coalesced dump of the 20 KB of tables
    for (int t = lane; t < WL_LEVELS * TSLOTS; t += 64) {
        tkeys[t] = ltk[t]; tval0[t] = ltv0[t]; tval1[t] = ltv1[t];
    }
}

// K2: one WAVE per seed. r2+hop3 inline; scatter WL msg; cross via global table
// probe; self_e via per-block LDS counting table (sum of c^2).
__global__ void __launch_bounds__(64)
ego_kernel(const unsigned* __restrict__ hinit,
           const u64* __restrict__ Adense,
           const unsigned* __restrict__ tkeys, const u64* __restrict__ tval0,
           const u64* __restrict__ tval1,
           const float* __restrict__ selfg, float* __restrict__ out) {
    const int i    = blockIdx.x;
    const int lane = threadIdx.x;
    const int w    = lane & 31;
    const int hwp  = lane >> 5;

    __shared__ u64 arow[WORDS];
    __shared__ u64 r2s[WORDS];
    __shared__ u64 mmask[WORDS];
    __shared__ unsigned pfx[WORDS];
    __shared__ unsigned idlist[IDCAP];
    __shared__ unsigned members[MAX_EGO];
    __shared__ unsigned msgacc[MAX_EGO];
    __shared__ __align__(16) unsigned adjs[MAX_EGO][4];
    __shared__ unsigned ctk[TSLOTS];    // self_e counting table: keys
    __shared__ unsigned ccnt[TSLOTS];   // self_e counting table: counts
    __shared__ float    selff_s[FILTERS];
    __shared__ unsigned cross_sh[FILTERS];
    __shared__ unsigned selfe_sh;

    if (lane < FILTERS) selff_s[lane] = selfg[lane];
    #pragma unroll
    for (int t = lane; t < MAX_EGO * 4; t += 64) ((unsigned*)adjs)[t] = 0;
    if (lane < WORDS) arow[lane] = Adense[(size_t)i * WORDS + lane];
    __syncthreads();

    // ---- extract N1 ids ----
    int n1;
    {
        u64 v = arow[w];
        int pc = __popcll(v);
        int incl = pc;
        for (int d = 1; d < 32; d <<= 1) {
            int t2 = __shfl_up(incl, d, 32);
            if (w >= d) incl += t2;
        }
        int ex = incl - pc;
        u64 vv = v; int r = 0;
        while (vv) {
            int b = __ffsll(vv) - 1; vv &= vv - 1;
            if (ex + r < IDCAP) idlist[ex + r] = (unsigned)((w << 6) + b);
            ++r;
        }
        n1 = min(__shfl(incl, 31, 32), IDCAP);
    }
    __syncthreads();

    // ---- r2 word: arow | I | OR of N1 rows (8-deep batched per half-wave) ----
    u64 racc = arow[w];
    if ((i >> 6) == w) racc |= 1ull << (i & 63);
    for (int t = hwp; t < n1; t += 16) {
        u64 vb[8];
        #pragma unroll
        for (int k = 0; k < 8; ++k) {
            int tk = t + 2 * k;
            vb[k] = (tk < n1) ? Adense[(size_t)idlist[tk] * WORDS + w] : 0ull;
        }
        racc |= vb[0] | vb[1] | vb[2] | vb[3] | vb[4] | vb[5] | vb[6] | vb[7];
    }
    racc |= __shfl_xor(racc, 32, 64);
    r2s[w] = racc;
    __syncthreads();

    // ---- extract N2 ids ----
    int n2;
    {
        u64 v = r2s[w];
        int pc = __popcll(v);
        int incl = pc;
        for (int d = 1; d < 32; d <<= 1) {
            int t2 = __shfl_up(incl, d, 32);
            if (w >= d) incl += t2;
        }
        int ex = incl - pc;
        u64 vv = v; int r = 0;
        while (vv) {
            int b = __ffsll(vv) - 1; vv &= vv - 1;
            if (ex + r < IDCAP) idlist[ex + r] = (unsigned)((w << 6) + b);
            ++r;
        }
        n2 = min(__shfl(incl, 31, 32), IDCAP);
    }
    __syncthreads();

    // ---- r3 word: r2 | OR of N2 rows (8-deep batched) ----
    u64 acc3 = racc;
    for (int t = hwp; t < n2; t += 16) {
        u64 vb[8];
        #pragma unroll
        for (int k = 0; k < 8; ++k) {
            int tk = t + 2 * k;
            vb[k] = (tk < n2) ? Adense[(size_t)idlist[tk] * WORDS + w] : 0ull;
        }
        acc3 |= vb[0] | vb[1] | vb[2] | vb[3] | vb[4] | vb[5] | vb[6] | vb[7];
    }
    acc3 |= __shfl_xor(acc3, 32, 64);

    // ---- member mask trim (seed + 127 smallest-index members) ----
    int S;
    {
        u64 v = acc3;
        int seedw = i >> 6;
        u64 seedbit = 1ull << (i & 63);
        if (w == seedw) v &= ~seedbit;
        int pc = __popcll(v);
        int incl = pc;
        for (int d = 1; d < 32; d <<= 1) {
            int t2 = __shfl_up(incl, d, 32);
            if (w >= d) incl += t2;
        }
        int excl = incl - pc;
        const int keep = MAX_EGO - 1;
        if (excl >= keep) {
            v = 0;
        } else {
            int allow = keep - excl;
            while (pc > allow) {
                v &= ~(1ull << (63 - __clzll(v)));
                --pc;
            }
        }
        if (w == seedw) v |= seedbit;
        mmask[w] = v;
        int pc2 = __popcll(v);
        int incl2 = pc2;
        for (int d = 1; d < 32; d <<= 1) {
            int t2 = __shfl_up(incl2, d, 32);
            if (w >= d) incl2 += t2;
        }
        int ex2 = incl2 - pc2;
        pfx[w] = (unsigned)ex2;
        u64 vv = v;
        int r = 0;
        while (vv) {
            int b = __ffsll(vv) - 1;
            vv &= vv - 1;
            members[ex2 + r] = (unsigned)((w << 6) + b);
            ++r;
        }
        S = __shfl(incl2, 31, 32);
    }
    __syncthreads();
    const int s0 = lane, s1 = lane + 64;
    const bool p0 = (s0 < S), p1 = (s1 < S);

    // ---- initial WL labels: one gather from precomputed hinit ----
    unsigned hv0 = 0, hv1 = 0;
    if (p0) hv0 = hinit[members[s0]];
    if (p1) hv1 = hinit[members[s1]];

    // ---- compact ego adjacency (half-wave per slot, 8-deep load batch) ----
    {
        const u64 mw = mmask[w];
        const unsigned base = pfx[w];
        for (int t = hwp; t < S; t += 16) {
            u64 vb[8];
            int ti[8];
            #pragma unroll
            for (int k = 0; k < 8; ++k) {
                ti[k] = t + 2 * k;
                vb[k] = (ti[k] < S) ? (Adense[(size_t)members[ti[k]] * WORDS + w] & mw) : 0ull;
            }
            #pragma unroll
            for (int k = 0; k < 8; ++k) {
                u64 v = vb[k];
                while (v) {
                    int b = __ffsll(v) - 1; v &= v - 1;
                    int slot = (int)base + __popcll(mw & ((1ull << b) - 1));
                    atomicOr(&adjs[ti[k]][slot >> 5], 1u << (slot & 31));
                }
            }
        }
    }
    __syncthreads();

    uint4 aw0 = *(const uint4*)adjs[s0];
    uint4 aw1 = *(const uint4*)adjs[s1];

    // ---- 4 WL levels: scatter-msg refine + probe cross + counting-table self ----
    u64 accA = 0, accB = 0;
    unsigned selfeReg = 0;

    for (int t = 0; t < WL_LEVELS; ++t) {
        if (t > 0) {
            msgacc[lane] = 0u; msgacc[lane + 64] = 0u;
            __syncthreads();
            if (p0) {
                unsigned mixv = mixu(hv0);
                unsigned bw[4] = {aw0.x, aw0.y, aw0.z, aw0.w};
                #pragma unroll
                for (int ww = 0; ww < 4; ++ww) {
                    unsigned bits = bw[ww];
                    while (bits) { int l = __ffs(bits) - 1; bits &= bits - 1;
                                   atomicAdd(&msgacc[(ww << 5) + l], mixv); }
                }
            }
            if (p1) {
                unsigned mixv = mixu(hv1);
                unsigned bw[4] = {aw1.x, aw1.y, aw1.z, aw1.w};
                #pragma unroll
                for (int ww = 0; ww < 4; ++ww) {
                    unsigned bits = bw[ww];
                    while (bits) { int l = __ffs(bits) - 1; bits &= bits - 1;
                                   atomicAdd(&msgacc[(ww << 5) + l], mixv); }
                }
            }
            __syncthreads();
            if (p0) hv0 = mixu(hv0 * 0x9E3779B1u + msgacc[s0]);
            if (p1) hv1 = mixu(hv1 * 0x9E3779B1u + msgacc[s1]);
        }

        // zero self_e counting table
        #pragma unroll
        for (int q = 0; q < 4; ++q) { ctk[lane + 64 * q] = 0u; ccnt[lane + 64 * q] = 0u; }
        __syncthreads();

        // cross probes (global table, L1-resident) — issue early
        const unsigned* tk = tkeys + t * TSLOTS;
        if (p0) {
            int p = (int)(hv0 & (TSLOTS - 1));
            unsigned k;
            while ((k = tk[p]) != 0u && k != hv0) p = (p + 1) & (TSLOTS - 1);
            if (k == hv0) { accA += tval0[t * TSLOTS + p]; accB += tval1[t * TSLOTS + p]; }
        }
        if (p1) {
            int p = (int)(hv1 & (TSLOTS - 1));
            unsigned k;
            while ((k = tk[p]) != 0u && k != hv1) p = (p + 1) & (TSLOTS - 1);
            if (k == hv1) { accA += tval0[t * TSLOTS + p]; accB += tval1[t * TSLOTS + p]; }
        }

        // self_e inserts
        if (p0) {
            int p = (int)(hv0 & (TSLOTS - 1));
            for (;;) {
                unsigned old = atomicCAS(&ctk[p], 0u, hv0);
                if (old == 0u || old == hv0) break;
                p = (p + 1) & (TSLOTS - 1);
            }
            atomicAdd(&ccnt[p], 1u);
        }
        if (p1) {
            int p = (int)(hv1 & (TSLOTS - 1));
            for (;;) {
                unsigned old = atomicCAS(&ctk[p], 0u, hv1);
                if (old == 0u || old == hv1) break;
                p = (p + 1) & (TSLOTS - 1);
            }
            atomicAdd(&ccnt[p], 1u);
        }
        __syncthreads();

        // self_e = sum over table of count^2 (4 slots per lane)
        #pragma unroll
        for (int q = 0; q < 4; ++q) {
            unsigned c = ccnt[lane + 64 * q];
            selfeReg += c * c;
        }
        __syncthreads();
    }

    // ---- unpack packed cross counts, wave reduction, output ----
    unsigned crossReg[FILTERS];
    #pragma unroll
    for (int k = 0; k < 8; ++k) {
        crossReg[k]     = (unsigned)((accA >> (8 * k)) & 0xFFull);
        crossReg[k + 8] = (unsigned)((accB >> (8 * k)) & 0xFFull);
    }
    #pragma unroll
    for (int f = 0; f < FILTERS; ++f) {
        unsigned v = crossReg[f];
        for (int o = 32; o > 0; o >>= 1) v += __shfl_down(v, o, 64);
        crossReg[f] = v;
    }
    {
        unsigned v = selfeReg;
        for (int o = 32; o > 0; o >>= 1) v += __shfl_down(v, o, 64);
        selfeReg = v;
    }
    if (lane == 0) {
        #pragma unroll
        for (int f = 0; f < FILTERS; ++f) cross_sh[f] = crossReg[f];
        selfe_sh = selfeReg;
    }
    __syncthreads();
    if (lane < FILTERS) {
        float se = (float)selfe_sh;
        float sf = selff_s[lane];
        float denom = sqrtf(se * sf);
        float v = (denom > 0.f) ? ((float)cross_sh[lane] / denom) : 0.f;
        out[(size_t)i * FILTERS + lane] = v;
    }
}

extern "C" void kernel_launch(void* const* d_in, const int* in_sizes, int n_in,
                              void* d_out, int out_size, void* d_ws, size_t ws_size,
                              hipStream_t stream) {
    const float* x  = (const float*)d_in[0];
    const int*   ei = (const int*)d_in[1];
    // d_in[2] = batch (unused: single graph)
    const float* A  = (const float*)d_in[3];
    const float* X  = (const float*)d_in[4];
    float* out = (float*)d_out;
    int E2 = in_sizes[1] / 2;   // directed edge count (both directions present)

    char* ws = (char*)d_ws;
    const size_t ADJ_BYTES = (size_t)N_NODES * WORDS * sizeof(u64); // 512 KB
    u64* Adense = (u64*)(ws);
    unsigned* tkeys = (unsigned*)(ws + ADJ_BYTES);                   // 4 KB
    u64*      tval0 = (u64*)     (ws + ADJ_BYTES + 4096);            // 8 KB
    u64*      tval1 = (u64*)     (ws + ADJ_BYTES + 4096 + 8192);     // 8 KB
    float*    selfg = (float*)   (ws + ADJ_BYTES + 4096 + 16384);    // 256 B
    unsigned* hinit = (unsigned*)(ws + ADJ_BYTES + 4096 + 16384 + 256); // 8 KB

    hipMemsetAsync(Adense, 0, ADJ_BYTES, stream);   // adjacency only
    int nbE = (E2 + 63) / 64;
    build_adj_kernel<<<nbE + 32 + 1, 64, 0, stream>>>(ei, E2, Adense, x, hinit,
                                                      A, X, tkeys, tval0, tval1, selfg);
    ego_kernel<<<N_NODES, 64, 0, stream>>>(hinit, Adense, tkeys, tval0, tval1, selfg, out);
}